// Round 1
// baseline (315.438 us; speedup 1.0000x reference)
//
#include <hip/hip_runtime.h>
#include <math.h>

#define TOKENS 32768
#define RDIM 512
#define NEXP 64
#define NK 256

// ---------------- Kernel A: expert centroids via sign-LUT bit tricks ----------------
// centroid[e][r] = mean_k sign( sum_x sign(atoms[e, idx[e,k,x], r]) * cw[e,k,x] )
// Pack per-k: i0,i1,i2 (4b each) + 8-entry sign LUT (8b) into one u32.
// Pack per-r: 16 atom sign bits into a u16. Then count negatives over k. Exact.
__global__ __launch_bounds__(256) void centroid_kernel(
    const float* __restrict__ atoms,
    const float* __restrict__ cw,
    const float* __restrict__ cl,
    float* __restrict__ cent)
{
    __shared__ unsigned pack[NK];
    const int e   = blockIdx.x;
    const int tid = threadIdx.x;

    {   // one k per thread (256 threads == NK)
        const int k = tid;
        unsigned u = 0;
        float w3[3];
        #pragma unroll
        for (int xx = 0; xx < 3; ++xx) {
            const float* cp = cl + ((((size_t)e * NK + k) * 3 + xx) << 4);
            float best = cp[0]; int bi = 0;
            #pragma unroll
            for (int a = 1; a < 16; ++a) {          // strict > keeps first max (jnp.argmax)
                float v = cp[a];
                if (v > best) { best = v; bi = a; }
            }
            u |= (unsigned)bi << (4 * xx);
            w3[xx] = cw[((size_t)e * NK + k) * 3 + xx];
        }
        unsigned lut = 0;
        #pragma unroll
        for (int c = 0; c < 8; ++c) {
            float val = ((c & 1) ? -w3[0] : w3[0])
                      + ((c & 2) ? -w3[1] : w3[1])
                      + ((c & 4) ? -w3[2] : w3[2]);
            lut |= (val < 0.f ? 1u : 0u) << c;
        }
        pack[k] = u | (lut << 16);
    }

    // atom sign bits for this thread's two r values (coalesced per a)
    unsigned B0 = 0, B1 = 0;
    #pragma unroll
    for (int a = 0; a < 16; ++a) {
        B0 |= (atoms[((size_t)e * 16 + a) * RDIM + tid]       < 0.f ? 1u : 0u) << a;
        B1 |= (atoms[((size_t)e * 16 + a) * RDIM + tid + 256] < 0.f ? 1u : 0u) << a;
    }
    __syncthreads();

    int n0 = 0, n1 = 0;
    for (int k = 0; k < NK; ++k) {
        unsigned u  = pack[k];                      // broadcast read: conflict-free
        unsigned i0 = u & 15u, i1 = (u >> 4) & 15u, i2 = (u >> 8) & 15u;
        unsigned c0 = ((B0 >> i0) & 1u) | (((B0 >> i1) & 1u) << 1) | (((B0 >> i2) & 1u) << 2);
        unsigned c1 = ((B1 >> i0) & 1u) | (((B1 >> i1) & 1u) << 1) | (((B1 >> i2) & 1u) << 2);
        n0 += (u >> (16 + c0)) & 1u;
        n1 += (u >> (16 + c1)) & 1u;
    }
    // sum_k(+-1) = 256 - 2n -> mean = 1 - n/128 (exact in fp32)
    cent[(size_t)e * RDIM + tid]       = 1.f - (float)n0 * (1.f / 128.f);
    cent[(size_t)e * RDIM + tid + 256] = 1.f - (float)n1 * (1.f / 128.f);
}

// ---------------- Kernel B: fused router GEMM + softmax + top2 + combine + aux ----------------
// Block = 64 tokens (lane = token) x 4 waves (wave = k-partition of 128).
// Each thread holds 64 fp32 logit accumulators. router_w addresses are
// wave-uniform (readfirstlane-laundered) -> scalar loads, SGPR-operand FMAs.
__global__ __launch_bounds__(256, 2) void moe_main(
    const float* __restrict__ x,
    const float* __restrict__ w,
    const float* __restrict__ cent,
    float* __restrict__ out,
    float* __restrict__ aux_sum,
    unsigned* __restrict__ aux_cnt)
{
    __shared__ float    lp[2][64][65];   // padded: stride 65 -> conflict-free
    __shared__ float    s_aux[64];
    __shared__ unsigned s_cnt[64];

    const int tid    = threadIdx.x;
    const int lane   = tid & 63;
    const int wave   = tid >> 6;
    const int token0 = blockIdx.x * 64;

    const int k0 = __builtin_amdgcn_readfirstlane(wave * 128);
    const float* xrow = x + (size_t)(token0 + lane) * RDIM + k0;
    const float* wk   = w + k0;

    float acc[NEXP];
    #pragma unroll
    for (int e = 0; e < NEXP; ++e) acc[e] = 0.f;

    #pragma unroll 2
    for (int j = 0; j < 128; j += 4) {
        const float4 xv = *(const float4*)(xrow + j);
        #pragma unroll
        for (int e = 0; e < NEXP; ++e) {
            const float* wr = wk + e * RDIM + j;   // wave-uniform address
            float a = acc[e];
            a = fmaf(xv.x, wr[0], a);
            a = fmaf(xv.y, wr[1], a);
            a = fmaf(xv.z, wr[2], a);
            a = fmaf(xv.w, wr[3], a);
            acc[e] = a;
        }
    }

    // Deterministic cross-wave combine: waves 2,3 write planes, waves 0,1 add.
    if (wave >= 2) {
        #pragma unroll
        for (int e = 0; e < NEXP; ++e) lp[wave - 2][lane][e] = acc[e];
    }
    if (tid < 64) { s_aux[tid] = 0.f; s_cnt[tid] = 0u; }
    __syncthreads();
    if (wave < 2) {
        #pragma unroll
        for (int e = 0; e < NEXP; ++e) lp[wave][lane][e] += acc[e];
    }
    __syncthreads();

    // Epilogue: each wave handles 16 tokens; lane = expert role.
    float regsum = 0.f;
    int   regcnt = 0;
    const int e = lane;
    for (int tt = 0; tt < 16; ++tt) {
        const int t = wave * 16 + tt;
        const float val = lp[0][t][e] + lp[1][t][e];

        // top-1 with lower-index tie-break
        float m1 = val; int i1 = e;
        #pragma unroll
        for (int off = 32; off; off >>= 1) {
            float ov = __shfl_xor(m1, off);
            int   oi = __shfl_xor(i1, off);
            if (ov > m1 || (ov == m1 && oi < i1)) { m1 = ov; i1 = oi; }
        }
        // top-2
        float m2 = (e == i1) ? -INFINITY : val; int i2 = e;
        #pragma unroll
        for (int off = 32; off; off >>= 1) {
            float ov = __shfl_xor(m2, off);
            int   oi = __shfl_xor(i2, off);
            if (ov > m2 || (ov == m2 && oi < i2)) { m2 = ov; i2 = oi; }
        }
        // full softmax (aux)
        const float ex = expf(val - m1);
        float Z = ex;
        #pragma unroll
        for (int off = 32; off; off >>= 1) Z += __shfl_xor(Z, off);
        regsum += ex / Z;
        regcnt += (ex > 0.f) ? 1 : 0;

        // normalized top-2 gates: g1 = p1/(p1+p2) = 1/(1+exp(l2-l1))
        const float ed  = expf(m2 - m1);
        const float inv = 1.f / (1.f + ed);
        const float g1 = inv, g2 = ed * inv;

        const float4* c1 = (const float4*)(cent + (size_t)i1 * RDIM);
        const float4* c2 = (const float4*)(cent + (size_t)i2 * RDIM);
        float4* op = (float4*)(out + (size_t)(token0 + t) * RDIM);
        float4 a0 = c1[e],      b0 = c2[e];
        float4 a1 = c1[e + 64], b1 = c2[e + 64];
        float4 r0, r1;
        r0.x = fmaf(g1, a0.x, g2 * b0.x); r0.y = fmaf(g1, a0.y, g2 * b0.y);
        r0.z = fmaf(g1, a0.z, g2 * b0.z); r0.w = fmaf(g1, a0.w, g2 * b0.w);
        r1.x = fmaf(g1, a1.x, g2 * b1.x); r1.y = fmaf(g1, a1.y, g2 * b1.y);
        r1.z = fmaf(g1, a1.z, g2 * b1.z); r1.w = fmaf(g1, a1.w, g2 * b1.w);
        op[e]      = r0;
        op[e + 64] = r1;
    }

    atomicAdd(&s_aux[e], regsum);
    atomicAdd(&s_cnt[e], (unsigned)regcnt);
    __syncthreads();
    if (tid < 64) {
        atomicAdd(aux_sum + tid, s_aux[tid]);
        atomicAdd(aux_cnt + tid, s_cnt[tid]);
    }
}

// ---------------- Kernel C: aux loss finalize ----------------
__global__ __launch_bounds__(64) void aux_kernel(
    const float* __restrict__ sums,
    const unsigned* __restrict__ cnts,
    float* __restrict__ out_aux)
{
    const int e = threadIdx.x;
    float v = (sums[e] * (1.f / (float)TOKENS)) * ((float)cnts[e] * (1.f / (float)TOKENS));
    #pragma unroll
    for (int off = 32; off; off >>= 1) v += __shfl_xor(v, off);
    if (e == 0) out_aux[0] = (float)NEXP * v;
}

extern "C" void kernel_launch(void* const* d_in, const int* in_sizes, int n_in,
                              void* d_out, int out_size, void* d_ws, size_t ws_size,
                              hipStream_t stream) {
    const float* x     = (const float*)d_in[0];  // (8,4096,512)
    const float* rw    = (const float*)d_in[1];  // (64,512)
    const float* atoms = (const float*)d_in[2];  // (64,16,512)
    const float* cwts  = (const float*)d_in[3];  // (64,256,3)
    const float* clog  = (const float*)d_in[4];  // (64,256,3,16)
    float* out = (float*)d_out;

    float*    aux_sum = (float*)d_ws;                       // 64 floats
    unsigned* aux_cnt = (unsigned*)((char*)d_ws + 256);     // 64 uints
    float*    cent    = (float*)((char*)d_ws + 512);        // 64*512 floats

    hipMemsetAsync(d_ws, 0, 512, stream);
    centroid_kernel<<<64, 256, 0, stream>>>(atoms, cwts, clog, cent);
    moe_main<<<512, 256, 0, stream>>>(x, rw, cent, out, aux_sum, aux_cnt);
    aux_kernel<<<1, 64, 0, stream>>>(aux_sum, aux_cnt, out + (size_t)TOKENS * RDIM);
}

// Round 2
// 228.582 us; speedup vs baseline: 1.3800x; 1.3800x over previous
//
#include <hip/hip_runtime.h>
#include <math.h>

#define TOKENS 32768
#define RDIM 512
#define NEXP 64
#define NK 256

#define WPB 8      // waves per block (k-partitions)
#define KPW 64     // k elements per wave (512/8)
#define GT 16      // tokens per group
#define TPB 64     // tokens per block

// ---------------- Kernel A: expert centroids via sign-LUT bit tricks ----------------
// 128 blocks: (expert, r-half). Pack work duplicated per half (cheap).
__global__ __launch_bounds__(256) void centroid_kernel(
    const float* __restrict__ atoms,
    const float* __restrict__ cw,
    const float* __restrict__ cl,
    float* __restrict__ cent)
{
    __shared__ unsigned pack[NK];
    const int e    = blockIdx.x >> 1;
    const int half = blockIdx.x & 1;
    const int tid  = threadIdx.x;

    {   // one k per thread (256 threads == NK)
        const int k = tid;
        unsigned u = 0;
        float w3[3];
        #pragma unroll
        for (int xx = 0; xx < 3; ++xx) {
            const float* cp = cl + ((((size_t)e * NK + k) * 3 + xx) << 4);
            float best = cp[0]; int bi = 0;
            #pragma unroll
            for (int a = 1; a < 16; ++a) {          // strict > keeps first max (jnp.argmax)
                float v = cp[a];
                if (v > best) { best = v; bi = a; }
            }
            u |= (unsigned)bi << (4 * xx);
            w3[xx] = cw[((size_t)e * NK + k) * 3 + xx];
        }
        unsigned lut = 0;
        #pragma unroll
        for (int c = 0; c < 8; ++c) {
            float val = ((c & 1) ? -w3[0] : w3[0])
                      + ((c & 2) ? -w3[1] : w3[1])
                      + ((c & 4) ? -w3[2] : w3[2]);
            lut |= (val < 0.f ? 1u : 0u) << c;
        }
        pack[k] = u | (lut << 16);
    }

    const int r = half * 256 + tid;
    unsigned B0 = 0;
    #pragma unroll
    for (int a = 0; a < 16; ++a)
        B0 |= (atoms[((size_t)e * 16 + a) * RDIM + r] < 0.f ? 1u : 0u) << a;
    __syncthreads();

    int n0 = 0;
    for (int k = 0; k < NK; ++k) {
        unsigned u  = pack[k];                      // broadcast read: conflict-free
        unsigned i0 = u & 15u, i1 = (u >> 4) & 15u, i2 = (u >> 8) & 15u;
        unsigned c0 = ((B0 >> i0) & 1u) | (((B0 >> i1) & 1u) << 1) | (((B0 >> i2) & 1u) << 2);
        n0 += (u >> (16 + c0)) & 1u;
    }
    cent[(size_t)e * RDIM + r] = 1.f - (float)n0 * (1.f / 128.f);
}

// ---------------- Kernel B: fused router GEMM + softmax + top2 + combine + aux ----------------
// 512-thread block = 8 waves. lane = expert (E=64), wave = k-partition of 64.
// w[e][k-slice] lives in 16 float4 VGPRs per thread (loaded once).
// x is broadcast via wave-uniform global loads (single transaction + broadcast).
__global__ __launch_bounds__(512, 4) void moe_main(
    const float* __restrict__ x,
    const float* __restrict__ w,
    const float* __restrict__ cent,
    float* __restrict__ out,
    float* __restrict__ aux_sum,
    unsigned* __restrict__ aux_cnt)
{
    __shared__ float    lp[WPB][GT][64];   // 32 KB; lane-contiguous inner dim
    __shared__ float    s_aux[64];
    __shared__ unsigned s_cnt[64];

    const int tid    = threadIdx.x;
    const int e      = tid & 63;                                   // lane = expert
    const int wave   = __builtin_amdgcn_readfirstlane(tid >> 6);   // SGPR, truly uniform
    const int token0 = blockIdx.x * TPB;

    // ---- preload this thread's w slice: w[e][wave*64 .. wave*64+64) ----
    float4 wr[16];
    {
        const float4* wrow = (const float4*)(w + (size_t)e * RDIM + wave * KPW);
        #pragma unroll
        for (int i = 0; i < 16; ++i) wr[i] = wrow[i];
    }

    if (tid < 64) { s_aux[tid] = 0.f; s_cnt[tid] = 0u; }

    float regsum = 0.f;
    int   regcnt = 0;

    for (int g = 0; g < TPB / GT; ++g) {
        // ---- partial logits for GT tokens (64 FMA per token per thread) ----
        float acc[GT];
        const float* xb = x + (size_t)(token0 + g * GT) * RDIM + wave * KPW;
        #pragma unroll
        for (int t = 0; t < GT; ++t) {
            const float4* xp = (const float4*)(xb + (size_t)t * RDIM);  // wave-uniform
            float a0 = 0.f, a1 = 0.f, a2 = 0.f, a3 = 0.f;
            #pragma unroll
            for (int i = 0; i < 16; ++i) {
                const float4 xv = xp[i];
                a0 = fmaf(xv.x, wr[i].x, a0);
                a1 = fmaf(xv.y, wr[i].y, a1);
                a2 = fmaf(xv.z, wr[i].z, a2);
                a3 = fmaf(xv.w, wr[i].w, a3);
            }
            acc[t] = (a0 + a1) + (a2 + a3);
        }

        __syncthreads();   // previous group's epilogue reads of lp are done
        #pragma unroll
        for (int t = 0; t < GT; ++t) lp[wave][t][e] = acc[t];
        __syncthreads();

        // ---- epilogue: each wave owns 2 of the 16 tokens ----
        #pragma unroll
        for (int s = 0; s < GT / WPB; ++s) {
            const int tt = wave * (GT / WPB) + s;
            const int t  = token0 + g * GT + tt;

            float val = 0.f;
            #pragma unroll
            for (int j = 0; j < WPB; ++j) val += lp[j][tt][e];  // fixed order: deterministic

            // top-1 with lower-index tie-break (matches lax.top_k)
            float m1 = val; int i1 = e;
            #pragma unroll
            for (int off = 32; off; off >>= 1) {
                float ov = __shfl_xor(m1, off);
                int   oi = __shfl_xor(i1, off);
                if (ov > m1 || (ov == m1 && oi < i1)) { m1 = ov; i1 = oi; }
            }
            // top-2
            float m2 = (e == i1) ? -INFINITY : val; int i2 = e;
            #pragma unroll
            for (int off = 32; off; off >>= 1) {
                float ov = __shfl_xor(m2, off);
                int   oi = __shfl_xor(i2, off);
                if (ov > m2 || (ov == m2 && oi < i2)) { m2 = ov; i2 = oi; }
            }
            // full softmax (aux)
            const float ex = expf(val - m1);
            float Z = ex;
            #pragma unroll
            for (int off = 32; off; off >>= 1) Z += __shfl_xor(Z, off);
            regsum += ex / Z;
            regcnt += (ex > 0.f) ? 1 : 0;

            // normalized top-2 gates: g1 = 1/(1+exp(l2-l1))
            const float ed  = expf(m2 - m1);
            const float inv = 1.f / (1.f + ed);
            const float g1 = inv, g2 = ed * inv;

            const float4* c1 = (const float4*)(cent + (size_t)i1 * RDIM);
            const float4* c2 = (const float4*)(cent + (size_t)i2 * RDIM);
            float4* op = (float4*)(out + (size_t)t * RDIM);
            float4 A0 = c1[e],      Bb0 = c2[e];
            float4 A1 = c1[e + 64], Bb1 = c2[e + 64];
            float4 r0, r1;
            r0.x = fmaf(g1, A0.x, g2 * Bb0.x); r0.y = fmaf(g1, A0.y, g2 * Bb0.y);
            r0.z = fmaf(g1, A0.z, g2 * Bb0.z); r0.w = fmaf(g1, A0.w, g2 * Bb0.w);
            r1.x = fmaf(g1, A1.x, g2 * Bb1.x); r1.y = fmaf(g1, A1.y, g2 * Bb1.y);
            r1.z = fmaf(g1, A1.z, g2 * Bb1.z); r1.w = fmaf(g1, A1.w, g2 * Bb1.w);
            op[e]      = r0;
            op[e + 64] = r1;
        }
    }

    atomicAdd(&s_aux[e], regsum);
    atomicAdd(&s_cnt[e], (unsigned)regcnt);
    __syncthreads();
    if (tid < 64) {
        atomicAdd(aux_sum + tid, s_aux[tid]);
        atomicAdd(aux_cnt + tid, s_cnt[tid]);
    }
}

// ---------------- Kernel C: aux loss finalize ----------------
__global__ __launch_bounds__(64) void aux_kernel(
    const float* __restrict__ sums,
    const unsigned* __restrict__ cnts,
    float* __restrict__ out_aux)
{
    const int e = threadIdx.x;
    float v = (sums[e] * (1.f / (float)TOKENS)) * ((float)cnts[e] * (1.f / (float)TOKENS));
    #pragma unroll
    for (int off = 32; off; off >>= 1) v += __shfl_xor(v, off);
    if (e == 0) out_aux[0] = (float)NEXP * v;
}

extern "C" void kernel_launch(void* const* d_in, const int* in_sizes, int n_in,
                              void* d_out, int out_size, void* d_ws, size_t ws_size,
                              hipStream_t stream) {
    const float* x     = (const float*)d_in[0];  // (8,4096,512)
    const float* rw    = (const float*)d_in[1];  // (64,512)
    const float* atoms = (const float*)d_in[2];  // (64,16,512)
    const float* cwts  = (const float*)d_in[3];  // (64,256,3)
    const float* clog  = (const float*)d_in[4];  // (64,256,3,16)
    float* out = (float*)d_out;

    float*    aux_sum = (float*)d_ws;                       // 64 floats
    unsigned* aux_cnt = (unsigned*)((char*)d_ws + 256);     // 64 uints
    float*    cent    = (float*)((char*)d_ws + 512);        // 64*512 floats

    hipMemsetAsync(d_ws, 0, 512, stream);
    centroid_kernel<<<128, 256, 0, stream>>>(atoms, cwts, clog, cent);
    moe_main<<<512, 512, 0, stream>>>(x, rw, cent, out, aux_sum, aux_cnt);
    aux_kernel<<<1, 64, 0, stream>>>(aux_sum, aux_cnt, out + (size_t)TOKENS * RDIM);
}

// Round 3
// 216.599 us; speedup vs baseline: 1.4563x; 1.0553x over previous
//
#include <hip/hip_runtime.h>
#include <math.h>

#define TOKENS 32768
#define RDIM 512
#define NEXP 64
#define NK 256

// ---------------- Kernel A: expert centroids via sign-LUT bit tricks ----------------
// 128 blocks: (expert, r-half). Block 0 also zero-inits the aux accumulators.
__global__ __launch_bounds__(256) void centroid_kernel(
    const float* __restrict__ atoms,
    const float* __restrict__ cw,
    const float* __restrict__ cl,
    float* __restrict__ cent,
    float* __restrict__ aux_sum,
    unsigned* __restrict__ aux_cnt)
{
    __shared__ unsigned pack[NK];
    const int e    = blockIdx.x >> 1;
    const int half = blockIdx.x & 1;
    const int tid  = threadIdx.x;

    if (blockIdx.x == 0 && tid < 64) { aux_sum[tid] = 0.f; aux_cnt[tid] = 0u; }

    {   // one k per thread (256 threads == NK)
        const int k = tid;
        unsigned u = 0;
        float w3[3];
        #pragma unroll
        for (int xx = 0; xx < 3; ++xx) {
            const float* cp = cl + ((((size_t)e * NK + k) * 3 + xx) << 4);
            float best = cp[0]; int bi = 0;
            #pragma unroll
            for (int a = 1; a < 16; ++a) {          // strict > keeps first max (jnp.argmax)
                float v = cp[a];
                if (v > best) { best = v; bi = a; }
            }
            u |= (unsigned)bi << (4 * xx);
            w3[xx] = cw[((size_t)e * NK + k) * 3 + xx];
        }
        unsigned lut = 0;
        #pragma unroll
        for (int c = 0; c < 8; ++c) {
            float val = ((c & 1) ? -w3[0] : w3[0])
                      + ((c & 2) ? -w3[1] : w3[1])
                      + ((c & 4) ? -w3[2] : w3[2]);
            lut |= (val < 0.f ? 1u : 0u) << c;
        }
        pack[k] = u | (lut << 16);
    }

    const int r = half * 256 + tid;
    unsigned B0 = 0;
    #pragma unroll
    for (int a = 0; a < 16; ++a)
        B0 |= (atoms[((size_t)e * 16 + a) * RDIM + r] < 0.f ? 1u : 0u) << a;
    __syncthreads();

    int n0 = 0;
    for (int k = 0; k < NK; ++k) {
        unsigned u  = pack[k];                      // broadcast read: conflict-free
        unsigned i0 = u & 15u, i1 = (u >> 4) & 15u, i2 = (u >> 8) & 15u;
        unsigned c0 = ((B0 >> i0) & 1u) | (((B0 >> i1) & 1u) << 1) | (((B0 >> i2) & 1u) << 2);
        n0 += (u >> (16 + c0)) & 1u;
    }
    cent[(size_t)e * RDIM + r] = 1.f - (float)n0 * (1.f / 128.f);
}

// ---------------- Kernel B: register-tiled GEMM + fused MoE epilogue ----------------
// 256 threads = 4 waves. Mtile = 64 tokens, Ntile = 64 experts, K split 4x128 by wave.
// Wave lanes = 8x8 (li=token-sub, lj=expert-sub); per-thread 8x8 acc with stride-8
// interleaved ownership (conflict-free LDS). x/w staged [row][68] in 8 stages of
// 64 k-cols (16 per k-range), globals prefetched one stage ahead.
__global__ __launch_bounds__(256, 2) void moe_main(
    const float* __restrict__ x,
    const float* __restrict__ w,
    const float* __restrict__ cent,
    float* __restrict__ out,
    float* __restrict__ aux_sum,
    unsigned* __restrict__ aux_cnt)
{
    __shared__ float lds[2 * 64 * 68];   // 34.8 KB: staging; reused as logit planes
    __shared__ float s_aux[64];
    __shared__ unsigned s_cnt[64];

    float* xs = lds;
    float* wsh = lds + 64 * 68;

    const int tid  = threadIdx.x;
    const int lane = tid & 63;
    const int wave = __builtin_amdgcn_readfirstlane(tid >> 6);   // k-range 0..3
    const int li   = lane & 7;    // token sub-lane
    const int lj   = lane >> 3;   // expert sub-lane
    const int tok0 = blockIdx.x * 64;

    if (tid < 64) { s_aux[tid] = 0.f; s_cnt[tid] = 0u; }

    // staging mapping: row = tid>>2 (token for x / expert for w), kf = tid&3
    const int tx = tid >> 2;
    const int kf = tid & 3;
    const float* xg = x + (size_t)(tok0 + tx) * RDIM + kf * 4;
    const float* wg = w + (size_t)tx * RDIM + kf * 4;

    float acc[8][8];
    #pragma unroll
    for (int s = 0; s < 8; ++s)
        #pragma unroll
        for (int u = 0; u < 8; ++u) acc[s][u] = 0.f;

    // prefetch stage 0: 4 ranges x 16B for x and w
    float4 xr[4], wr[4];
    #pragma unroll
    for (int r = 0; r < 4; ++r) {
        xr[r] = *(const float4*)(xg + r * 128);
        wr[r] = *(const float4*)(wg + r * 128);
    }

    const int colbase = wave * 16;

    for (int st = 0; st < 8; ++st) {
        __syncthreads();                      // prior stage's LDS reads done
        #pragma unroll
        for (int r = 0; r < 4; ++r) {
            *(float4*)(xs  + tx * 68 + r * 16 + kf * 4) = xr[r];
            *(float4*)(wsh + tx * 68 + r * 16 + kf * 4) = wr[r];
        }
        __syncthreads();
        if (st < 7) {                         // prefetch next stage during compute
            const int o = (st + 1) * 16;
            #pragma unroll
            for (int r = 0; r < 4; ++r) {
                xr[r] = *(const float4*)(xg + r * 128 + o);
                wr[r] = *(const float4*)(wg + r * 128 + o);
            }
        }
        #pragma unroll
        for (int kq = 0; kq < 4; ++kq) {
            const int col = colbase + kq * 4;
            float4 xv[8], wv[8];
            #pragma unroll
            for (int s = 0; s < 8; ++s)
                xv[s] = *(const float4*)(xs + (li + 8 * s) * 68 + col);
            #pragma unroll
            for (int u = 0; u < 8; ++u)
                wv[u] = *(const float4*)(wsh + (lj + 8 * u) * 68 + col);
            #pragma unroll
            for (int s = 0; s < 8; ++s)
                #pragma unroll
                for (int u = 0; u < 8; ++u) {
                    float a = acc[s][u];
                    a = fmaf(xv[s].x, wv[u].x, a);
                    a = fmaf(xv[s].y, wv[u].y, a);
                    a = fmaf(xv[s].z, wv[u].z, a);
                    a = fmaf(xv[s].w, wv[u].w, a);
                    acc[s][u] = a;
                }
        }
    }

    // ---- deterministic 4-wave reduction into two logit planes (overlay LDS) ----
    __syncthreads();
    float* pA = lds;             // [64][66]
    float* pB = lds + 64 * 66;

    if (wave < 2) {
        float* P = (wave == 0) ? pA : pB;
        #pragma unroll
        for (int s = 0; s < 8; ++s)
            #pragma unroll
            for (int u = 0; u < 8; ++u)
                P[(li + 8 * s) * 66 + lj + 8 * u] = acc[s][u];
    }
    __syncthreads();
    if (wave >= 2) {
        float* P = (wave == 2) ? pA : pB;
        #pragma unroll
        for (int s = 0; s < 8; ++s)
            #pragma unroll
            for (int u = 0; u < 8; ++u)
                P[(li + 8 * s) * 66 + lj + 8 * u] += acc[s][u];
    }
    __syncthreads();

    // ---- per-token epilogue: wave handles 16 tokens, lane = expert ----
    float regsum = 0.f;
    int   regcnt = 0;
    const int e = lane;
    for (int s2 = 0; s2 < 16; ++s2) {
        const int tt = wave * 16 + s2;
        const float val = pA[tt * 66 + e] + pB[tt * 66 + e];   // (w0+w2)+(w1+w3)

        // top-1 with lower-index tie-break (matches lax.top_k)
        float m1 = val; int i1 = e;
        #pragma unroll
        for (int off = 32; off; off >>= 1) {
            float ov = __shfl_xor(m1, off);
            int   oi = __shfl_xor(i1, off);
            if (ov > m1 || (ov == m1 && oi < i1)) { m1 = ov; i1 = oi; }
        }
        // top-2
        float m2 = (e == i1) ? -INFINITY : val; int i2 = e;
        #pragma unroll
        for (int off = 32; off; off >>= 1) {
            float ov = __shfl_xor(m2, off);
            int   oi = __shfl_xor(i2, off);
            if (ov > m2 || (ov == m2 && oi < i2)) { m2 = ov; i2 = oi; }
        }
        // full softmax (aux)
        const float ex = expf(val - m1);
        float Z = ex;
        #pragma unroll
        for (int off = 32; off; off >>= 1) Z += __shfl_xor(Z, off);
        regsum += ex / Z;
        regcnt += (ex > 0.f) ? 1 : 0;

        // normalized top-2 gates: g1 = 1/(1+exp(l2-l1))
        const float ed  = expf(m2 - m1);
        const float inv = 1.f / (1.f + ed);
        const float g1 = inv, g2 = ed * inv;

        const float4* c1 = (const float4*)(cent + (size_t)i1 * RDIM);
        const float4* c2 = (const float4*)(cent + (size_t)i2 * RDIM);
        float4* op = (float4*)(out + (size_t)(tok0 + tt) * RDIM);
        float4 A0 = c1[e],      Bb0 = c2[e];
        float4 A1 = c1[e + 64], Bb1 = c2[e + 64];
        float4 r0, r1;
        r0.x = fmaf(g1, A0.x, g2 * Bb0.x); r0.y = fmaf(g1, A0.y, g2 * Bb0.y);
        r0.z = fmaf(g1, A0.z, g2 * Bb0.z); r0.w = fmaf(g1, A0.w, g2 * Bb0.w);
        r1.x = fmaf(g1, A1.x, g2 * Bb1.x); r1.y = fmaf(g1, A1.y, g2 * Bb1.y);
        r1.z = fmaf(g1, A1.z, g2 * Bb1.z); r1.w = fmaf(g1, A1.w, g2 * Bb1.w);
        op[e]      = r0;
        op[e + 64] = r1;
    }

    atomicAdd(&s_aux[e], regsum);
    atomicAdd(&s_cnt[e], (unsigned)regcnt);
    __syncthreads();
    if (tid < 64) {
        atomicAdd(aux_sum + tid, s_aux[tid]);
        atomicAdd(aux_cnt + tid, s_cnt[tid]);
    }
}

// ---------------- Kernel C: aux loss finalize ----------------
__global__ __launch_bounds__(64) void aux_kernel(
    const float* __restrict__ sums,
    const unsigned* __restrict__ cnts,
    float* __restrict__ out_aux)
{
    const int e = threadIdx.x;
    float v = (sums[e] * (1.f / (float)TOKENS)) * ((float)cnts[e] * (1.f / (float)TOKENS));
    #pragma unroll
    for (int off = 32; off; off >>= 1) v += __shfl_xor(v, off);
    if (e == 0) out_aux[0] = (float)NEXP * v;
}

extern "C" void kernel_launch(void* const* d_in, const int* in_sizes, int n_in,
                              void* d_out, int out_size, void* d_ws, size_t ws_size,
                              hipStream_t stream) {
    const float* x     = (const float*)d_in[0];  // (8,4096,512)
    const float* rw    = (const float*)d_in[1];  // (64,512)
    const float* atoms = (const float*)d_in[2];  // (64,16,512)
    const float* cwts  = (const float*)d_in[3];  // (64,256,3)
    const float* clog  = (const float*)d_in[4];  // (64,256,3,16)
    float* out = (float*)d_out;

    float*    aux_sum = (float*)d_ws;                       // 64 floats
    unsigned* aux_cnt = (unsigned*)((char*)d_ws + 256);     // 64 uints
    float*    cent    = (float*)((char*)d_ws + 512);        // 64*512 floats

    centroid_kernel<<<128, 256, 0, stream>>>(atoms, cwts, clog, cent, aux_sum, aux_cnt);
    moe_main<<<512, 256, 0, stream>>>(x, rw, cent, out, aux_sum, aux_cnt);
    aux_kernel<<<1, 64, 0, stream>>>(aux_sum, aux_cnt, out + (size_t)TOKENS * RDIM);
}

// Round 4
// 213.867 us; speedup vs baseline: 1.4749x; 1.0128x over previous
//
#include <hip/hip_runtime.h>
#include <math.h>

#define TOKENS 32768
#define RDIM 512
#define NEXP 64
#define NK 256

// ---------------- Kernel A: expert centroids via sign-LUT bit tricks ----------------
// 128 blocks: (expert, r-half). Block 0 also zero-inits the aux accumulators.
__global__ __launch_bounds__(256) void centroid_kernel(
    const float* __restrict__ atoms,
    const float* __restrict__ cw,
    const float* __restrict__ cl,
    float* __restrict__ cent,
    float* __restrict__ aux_sum,
    unsigned* __restrict__ aux_cnt)
{
    __shared__ unsigned pack[NK];
    const int e    = blockIdx.x >> 1;
    const int half = blockIdx.x & 1;
    const int tid  = threadIdx.x;

    if (blockIdx.x == 0 && tid < 64) { aux_sum[tid] = 0.f; aux_cnt[tid] = 0u; }

    {   // one k per thread (256 threads == NK)
        const int k = tid;
        unsigned u = 0;
        float w3[3];
        #pragma unroll
        for (int xx = 0; xx < 3; ++xx) {
            const float* cp = cl + ((((size_t)e * NK + k) * 3 + xx) << 4);
            float v[16];
            *(float4*)(v + 0)  = *(const float4*)(cp + 0);
            *(float4*)(v + 4)  = *(const float4*)(cp + 4);
            *(float4*)(v + 8)  = *(const float4*)(cp + 8);
            *(float4*)(v + 12) = *(const float4*)(cp + 12);
            float best = v[0]; int bi = 0;
            #pragma unroll
            for (int a = 1; a < 16; ++a) {          // strict > keeps first max (jnp.argmax)
                if (v[a] > best) { best = v[a]; bi = a; }
            }
            u |= (unsigned)bi << (4 * xx);
            w3[xx] = cw[((size_t)e * NK + k) * 3 + xx];
        }
        unsigned lut = 0;
        #pragma unroll
        for (int c = 0; c < 8; ++c) {
            float val = ((c & 1) ? -w3[0] : w3[0])
                      + ((c & 2) ? -w3[1] : w3[1])
                      + ((c & 4) ? -w3[2] : w3[2]);
            lut |= (val < 0.f ? 1u : 0u) << c;
        }
        pack[k] = u | (lut << 16);
    }

    const int r = half * 256 + tid;
    unsigned B0 = 0;
    #pragma unroll
    for (int a = 0; a < 16; ++a)
        B0 |= (atoms[((size_t)e * 16 + a) * RDIM + r] < 0.f ? 1u : 0u) << a;
    __syncthreads();

    int n0 = 0;
    for (int k = 0; k < NK; ++k) {
        unsigned u  = pack[k];                      // broadcast read: conflict-free
        unsigned i0 = u & 15u, i1 = (u >> 4) & 15u, i2 = (u >> 8) & 15u;
        unsigned c0 = ((B0 >> i0) & 1u) | (((B0 >> i1) & 1u) << 1) | (((B0 >> i2) & 1u) << 2);
        n0 += (u >> (16 + c0)) & 1u;
    }
    cent[(size_t)e * RDIM + r] = 1.f - (float)n0 * (1.f / 128.f);
}

// ---------------- Kernel B: register-tiled GEMM (4x4 micro) + fused MoE epilogue ----
// 256 threads = 16x16 grid (ti=token-col, tj=expert-col). M=64 tok, N=64 exp,
// full K=512 per thread (no k-split -> deterministic sequential k order).
// LDS tiles in NATURAL [row][k] layout, stride 68 (16B-aligned rows, 2-way banks);
// fragments read ALONG k via ds_read_b128 (4 k-steps per read, no transpose).
// Rows owned interleaved (ti+16s / tj+16u) -> conflict-free reads.
__global__ __launch_bounds__(256) void moe_main(
    const float* __restrict__ x,
    const float* __restrict__ w,
    const float* __restrict__ cent,
    float* __restrict__ out,
    float* __restrict__ aux_sum,
    unsigned* __restrict__ aux_cnt)
{
    __shared__ float lds[2 * 64 * 68];   // 34.8 KB staging; reused as logit plane
    __shared__ float s_aux[64];
    __shared__ unsigned s_cnt[64];

    float* xs = lds;              // [64 tok][68]
    float* wsB = lds + 64 * 68;   // [64 exp][68]

    const int tid  = threadIdx.x;
    const int lane = tid & 63;
    const int wave = __builtin_amdgcn_readfirstlane(tid >> 6);
    const int ti   = tid & 15;    // token column
    const int tj   = tid >> 4;    // expert column (0..15)
    const int tok0 = blockIdx.x * 64;

    if (tid < 64) { s_aux[tid] = 0.f; s_cnt[tid] = 0u; }

    // staging: row = tid>>2 (token / expert), q = 16-float chunk
    const int tx = tid >> 2;
    const int q  = tid & 3;
    const float* xg = x + (size_t)(tok0 + tx) * RDIM + q * 16;
    const float* wg = w + (size_t)tx * RDIM + q * 16;

    float acc[4][4];
    #pragma unroll
    for (int s = 0; s < 4; ++s)
        #pragma unroll
        for (int u = 0; u < 4; ++u) acc[s][u] = 0.f;

    // prefetch stage 0
    float4 xr[4], wr_[4];
    #pragma unroll
    for (int j = 0; j < 4; ++j) {
        xr[j]  = *(const float4*)(xg + j * 4);
        wr_[j] = *(const float4*)(wg + j * 4);
    }

    for (int st = 0; st < 8; ++st) {
        __syncthreads();                      // prior stage's LDS reads done
        #pragma unroll
        for (int j = 0; j < 4; ++j) {
            *(float4*)(xs  + tx * 68 + q * 16 + j * 4) = xr[j];
            *(float4*)(wsB + tx * 68 + q * 16 + j * 4) = wr_[j];
        }
        __syncthreads();
        if (st < 7) {                         // prefetch next stage during compute
            const int o = (st + 1) * 64;
            #pragma unroll
            for (int j = 0; j < 4; ++j) {
                xr[j]  = *(const float4*)(xg + o + j * 4);
                wr_[j] = *(const float4*)(wg + o + j * 4);
            }
        }
        #pragma unroll 4
        for (int kk = 0; kk < 64; kk += 4) {
            float4 xv[4], wv[4];
            #pragma unroll
            for (int s = 0; s < 4; ++s)
                xv[s] = *(const float4*)(xs + (ti + 16 * s) * 68 + kk);
            #pragma unroll
            for (int u = 0; u < 4; ++u)
                wv[u] = *(const float4*)(wsB + (tj + 16 * u) * 68 + kk);
            #pragma unroll
            for (int s = 0; s < 4; ++s)
                #pragma unroll
                for (int u = 0; u < 4; ++u) {
                    float a = acc[s][u];
                    a = fmaf(xv[s].x, wv[u].x, a);
                    a = fmaf(xv[s].y, wv[u].y, a);
                    a = fmaf(xv[s].z, wv[u].z, a);
                    a = fmaf(xv[s].w, wv[u].w, a);
                    acc[s][u] = a;
                }
        }
    }

    // ---- logits to LDS plane [64 tok][66] (overlay on staging) ----
    __syncthreads();
    float* P = lds;
    #pragma unroll
    for (int s = 0; s < 4; ++s)
        #pragma unroll
        for (int u = 0; u < 4; ++u)
            P[(ti + 16 * s) * 66 + (tj + 16 * u)] = acc[s][u];
    __syncthreads();

    // ---- per-token epilogue: wave handles 16 tokens, lane = expert ----
    float regsum = 0.f;
    int   regcnt = 0;
    const int e = lane;
    for (int s2 = 0; s2 < 16; ++s2) {
        const int tt = wave * 16 + s2;
        const float val = P[tt * 66 + e];

        // top-1 with lower-index tie-break (matches lax.top_k)
        float m1 = val; int i1 = e;
        #pragma unroll
        for (int off = 32; off; off >>= 1) {
            float ov = __shfl_xor(m1, off);
            int   oi = __shfl_xor(i1, off);
            if (ov > m1 || (ov == m1 && oi < i1)) { m1 = ov; i1 = oi; }
        }
        // top-2
        float m2 = (e == i1) ? -INFINITY : val; int i2 = e;
        #pragma unroll
        for (int off = 32; off; off >>= 1) {
            float ov = __shfl_xor(m2, off);
            int   oi = __shfl_xor(i2, off);
            if (ov > m2 || (ov == m2 && oi < i2)) { m2 = ov; i2 = oi; }
        }
        // full softmax (aux)
        const float ex = expf(val - m1);
        float Z = ex;
        #pragma unroll
        for (int off = 32; off; off >>= 1) Z += __shfl_xor(Z, off);
        regsum += ex / Z;
        regcnt += (ex > 0.f) ? 1 : 0;

        // normalized top-2 gates: g1 = 1/(1+exp(l2-l1))
        const float ed  = expf(m2 - m1);
        const float inv = 1.f / (1.f + ed);
        const float g1 = inv, g2 = ed * inv;

        const float4* c1 = (const float4*)(cent + (size_t)i1 * RDIM);
        const float4* c2 = (const float4*)(cent + (size_t)i2 * RDIM);
        float4* op = (float4*)(out + (size_t)(tok0 + tt) * RDIM);
        float4 A0 = c1[e],      Bb0 = c2[e];
        float4 A1 = c1[e + 64], Bb1 = c2[e + 64];
        float4 r0, r1;
        r0.x = fmaf(g1, A0.x, g2 * Bb0.x); r0.y = fmaf(g1, A0.y, g2 * Bb0.y);
        r0.z = fmaf(g1, A0.z, g2 * Bb0.z); r0.w = fmaf(g1, A0.w, g2 * Bb0.w);
        r1.x = fmaf(g1, A1.x, g2 * Bb1.x); r1.y = fmaf(g1, A1.y, g2 * Bb1.y);
        r1.z = fmaf(g1, A1.z, g2 * Bb1.z); r1.w = fmaf(g1, A1.w, g2 * Bb1.w);
        op[e]      = r0;
        op[e + 64] = r1;
    }

    atomicAdd(&s_aux[e], regsum);
    atomicAdd(&s_cnt[e], (unsigned)regcnt);
    __syncthreads();
    if (tid < 64) {
        atomicAdd(aux_sum + tid, s_aux[tid]);
        atomicAdd(aux_cnt + tid, s_cnt[tid]);
    }
}

// ---------------- Kernel C: aux loss finalize ----------------
__global__ __launch_bounds__(64) void aux_kernel(
    const float* __restrict__ sums,
    const unsigned* __restrict__ cnts,
    float* __restrict__ out_aux)
{
    const int e = threadIdx.x;
    float v = (sums[e] * (1.f / (float)TOKENS)) * ((float)cnts[e] * (1.f / (float)TOKENS));
    #pragma unroll
    for (int off = 32; off; off >>= 1) v += __shfl_xor(v, off);
    if (e == 0) out_aux[0] = (float)NEXP * v;
}

extern "C" void kernel_launch(void* const* d_in, const int* in_sizes, int n_in,
                              void* d_out, int out_size, void* d_ws, size_t ws_size,
                              hipStream_t stream) {
    const float* x     = (const float*)d_in[0];  // (8,4096,512)
    const float* rw    = (const float*)d_in[1];  // (64,512)
    const float* atoms = (const float*)d_in[2];  // (64,16,512)
    const float* cwts  = (const float*)d_in[3];  // (64,256,3)
    const float* clog  = (const float*)d_in[4];  // (64,256,3,16)
    float* out = (float*)d_out;

    float*    aux_sum = (float*)d_ws;                       // 64 floats
    unsigned* aux_cnt = (unsigned*)((char*)d_ws + 256);     // 64 uints
    float*    cent    = (float*)((char*)d_ws + 512);        // 64*512 floats

    centroid_kernel<<<128, 256, 0, stream>>>(atoms, cwts, clog, cent, aux_sum, aux_cnt);
    moe_main<<<512, 256, 0, stream>>>(x, rw, cent, out, aux_sum, aux_cnt);
    aux_kernel<<<1, 64, 0, stream>>>(aux_sum, aux_cnt, out + (size_t)TOKENS * RDIM);
}